// Round 2
// baseline (480.571 us; speedup 1.0000x reference)
//
#include <hip/hip_runtime.h>

using u16 = unsigned short;
using u32 = unsigned int;

typedef __attribute__((ext_vector_type(8))) short short8;
typedef __attribute__((ext_vector_type(4))) float floatx4;

constexpr int TOKENS = 128;   // N (M dim of GEMMs)
constexpr int DM = 2560;      // D
constexpr int DI = 5120;      // DIN
constexpr int NS = 16;        // S
constexpr int NR = 160;       // R
constexpr int NP = 192;       // R + 2S

// workspace layout (floats)
constexpr size_t U_OFF    = 0;
constexpr size_t RES_OFF  = U_OFF   + (size_t)TOKENS * DI;
constexpr size_t DT_OFF   = RES_OFF + (size_t)TOKENS * DI;
constexpr size_t Z_OFF    = DT_OFF  + (size_t)TOKENS * DI;
constexpr size_t PROJ_OFF = Z_OFF   + (size_t)TOKENS * DI;
constexpr size_t OACC_OFF = PROJ_OFF + (size_t)TOKENS * NP;

__device__ __forceinline__ float bf2f(u16 h) {
  u32 u = ((u32)h) << 16;
  return __builtin_bit_cast(float, u);
}
__device__ __forceinline__ u16 f2bf(float f) {
  u32 u = __builtin_bit_cast(u32, f);
  u += 0x7FFFu + ((u >> 16) & 1u);   // RNE
  return (u16)(u >> 16);
}
__device__ __forceinline__ u32 pk2(float a, float b) {
  return (u32)f2bf(a) | ((u32)f2bf(b) << 16);
}

// scalar load of raw input element (bf16 or f32 per flag)
__device__ __forceinline__ float ldsc(const void* p, size_t i, bool bf) {
  return bf ? bf2f(((const u16*)p)[i]) : ((const float*)p)[i];
}
// load 8 consecutive elements as packed bf16 (uint4); i must be multiple of 8
__device__ __forceinline__ uint4 ld8(const void* p, size_t i, bool bf) {
  if (bf) return *(const uint4*)((const u16*)p + i);
  const float4* f = (const float4*)((const float*)p + i);
  float4 a = f[0], b = f[1];
  return (uint4){pk2(a.x, a.y), pk2(a.z, a.w), pk2(b.x, b.y), pk2(b.z, b.w)};
}

struct GemmP {
  const void* A; int lda; int a_ws;   // a_ws: A is f32 workspace
  const void* B; const void* B2;
  float* C; float* C2;
  int ldb; int ldc;
  int ksteps;          // K/32 per k-chunk; kstart = blockIdx.y*ksteps*32
  int nx_half;         // blockIdx.x >= nx_half -> B2/C2/epi2
  int epi1; int epi2;  // 0 none, 1 conv+silu, 2 softplus+bias
  int atomic_;
  const void* bias;
  const void* cs1; const void* cs2; const void* cs3; const void* cw;
  const u32* probe;    // first word of A_log: 0 => inputs f32, else bf16
};

// BM=128 BN=64 BK=32, 256 threads = 4 waves (2x2), wave tile 64x32 (4x2 mfma 16x16x32)
__global__ __launch_bounds__(256) void gemm_k(GemmP p) {
  __shared__ u16 As[128 * 40];  // [m][k], row stride 40 elems (80B, 16B-aligned, padded)
  __shared__ u16 Bs[32 * 64];   // [k][n] with 32B rotation swizzle per (k>>3)

  const bool bf = (p.probe[0] != 0u);
  const int tid = threadIdx.x;
  const int bx = blockIdx.x;
  const void* B = p.B; float* C = p.C; int epi = p.epi1;
  int nblk = bx;
  if (bx >= p.nx_half) { B = p.B2; C = p.C2; epi = p.epi2; nblk = bx - p.nx_half; }
  const int n0 = nblk * 64;
  const int kstart = blockIdx.y * p.ksteps * 32;

  const int wave = tid >> 6, lane = tid & 63;
  const int q = lane >> 4, l16 = lane & 15;
  const int wx = wave & 1, wy = wave >> 1;

  floatx4 acc[4][2];
#pragma unroll
  for (int mi = 0; mi < 4; mi++)
#pragma unroll
    for (int ni = 0; ni < 2; ni++) acc[mi][ni] = (floatx4){0.f, 0.f, 0.f, 0.f};

  const bool a_f32 = p.a_ws || !bf;

  for (int ks = 0; ks < p.ksteps; ks++) {
    const int kbase = kstart + ks * 32;
    // ---- stage: global loads into regs ----
    uint4 aW[2];
#pragma unroll
    for (int i = 0; i < 2; i++) {
      int id = tid + i * 256;
      int m = id >> 2, sg = id & 3;
      size_t base = (size_t)m * p.lda + kbase + sg * 8;
      if (!a_f32) {
        aW[i] = *(const uint4*)((const u16*)p.A + base);
      } else {
        const float4* af = (const float4*)((const float*)p.A + base);
        float4 f0 = af[0], f1 = af[1];
        aW[i] = (uint4){pk2(f0.x, f0.y), pk2(f0.z, f0.w), pk2(f1.x, f1.y), pk2(f1.z, f1.w)};
      }
    }
    const int bk = tid >> 3, bsg = tid & 7;
    uint4 bW = ld8(B, (size_t)(kbase + bk) * p.ldb + n0 + bsg * 8, bf);

    __syncthreads();  // prev compute done before overwriting LDS
#pragma unroll
    for (int i = 0; i < 2; i++) {
      int id = tid + i * 256;
      int m = id >> 2, sg = id & 3;
      *(uint4*)&As[m * 40 + sg * 8] = aW[i];
    }
    {
      int off = ((bsg << 4) + ((bk >> 3) << 5)) & 127;  // byte offset, 16B-aligned
      *(uint4*)&Bs[bk * 64 + (off >> 1)] = bW;
    }
    __syncthreads();

    // ---- compute ----
    short8 afr[4];
#pragma unroll
    for (int mi = 0; mi < 4; mi++)
      afr[mi] = __builtin_bit_cast(short8,
          *(const uint4*)&As[(wy * 64 + mi * 16 + l16) * 40 + q * 8]);
    short8 bfr[2];
#pragma unroll
    for (int ni = 0; ni < 2; ni++) {
      int nl2 = (wx * 32 + ni * 16 + l16) * 2;
      int boff = (nl2 + (q << 5)) & 127;
      const u16* bp = &Bs[q * 512 + (boff >> 1)];
      short8 b;
#pragma unroll
      for (int j = 0; j < 8; j++) b[j] = (short)bp[j * 64];
      bfr[ni] = b;
    }
#pragma unroll
    for (int mi = 0; mi < 4; mi++)
#pragma unroll
      for (int ni = 0; ni < 2; ni++)
        acc[mi][ni] = __builtin_amdgcn_mfma_f32_16x16x32_bf16(
            afr[mi], bfr[ni], acc[mi][ni], 0, 0, 0);
  }

  // ---- epilogue: D row = wy*64+mi*16+q*4+r, col = n0+wx*32+ni*16+l16 ----
#pragma unroll
  for (int ni = 0; ni < 2; ni++) {
    int col = n0 + wx * 32 + ni * 16 + l16;
    float w0 = 0, w1 = 0, w2 = 0, w3 = 0, bv = 0;
    if (epi == 1) {
      w0 = ldsc(p.cw, col, bf); w1 = ldsc(p.cw, DI + col, bf);
      w2 = ldsc(p.cw, 2 * DI + col, bf); w3 = ldsc(p.cw, 3 * DI + col, bf);
      bv = ldsc(p.bias, col, bf);
    } else if (epi == 2) {
      bv = ldsc(p.bias, col, bf);
    }
#pragma unroll
    for (int mi = 0; mi < 4; mi++) {
      floatx4 v = acc[mi][ni];
#pragma unroll
      for (int r = 0; r < 4; r++) {
        int row = wy * 64 + mi * 16 + q * 4 + r;
        float val = v[r];
        if (epi == 1) {
          size_t ix = (size_t)row * DI + col;
          float cv = bv + w0 * ldsc(p.cs1, ix, bf) + w1 * ldsc(p.cs2, ix, bf) +
                     w2 * ldsc(p.cs3, ix, bf) + w3 * val;
          val = cv / (1.0f + __expf(-cv));  // silu
        } else if (epi == 2) {
          float sv = val + bv;
          val = (sv > 20.0f) ? sv : log1pf(__expf(sv));  // softplus
        }
        size_t off = (size_t)row * p.ldc + col;
        if (p.atomic_) atomicAdd(&C[off], val);
        else C[off] = val;
      }
    }
  }
}

// SSM scan + fused * res. grid (DI/256, TOKENS)
__global__ __launch_bounds__(256) void ssm_k(
    const void* __restrict__ sstate, const void* __restrict__ alog,
    const void* __restrict__ dparam, const float* __restrict__ proj,
    const float* __restrict__ dt, const float* __restrict__ u,
    const float* __restrict__ res, float* __restrict__ z,
    const u32* __restrict__ probe) {
  const bool bf = (probe[0] != 0u);
  const int n = blockIdx.y;
  const int d = blockIdx.x * 256 + threadIdx.x;
  __shared__ float Bsh[NS], Csh[NS];
  if (threadIdx.x < NS)
    Bsh[threadIdx.x] = proj[(size_t)n * NP + NR + threadIdx.x];
  else if (threadIdx.x < 2 * NS)
    Csh[threadIdx.x - NS] = proj[(size_t)n * NP + NR + threadIdx.x];
  __syncthreads();
  const size_t nd = (size_t)n * DI + d;
  const float dtv = dt[nd], uv = u[nd], rv = res[nd];

  float stf[16], alf[16];
  if (bf) {
    u16 st[16], al[16];
    const uint4* sp = (const uint4*)((const u16*)sstate + nd * 16);
    *(uint4*)&st[0] = sp[0]; *(uint4*)&st[8] = sp[1];
    const uint4* ap = (const uint4*)((const u16*)alog + (size_t)d * 16);
    *(uint4*)&al[0] = ap[0]; *(uint4*)&al[8] = ap[1];
#pragma unroll
    for (int s = 0; s < 16; s++) { stf[s] = bf2f(st[s]); alf[s] = bf2f(al[s]); }
  } else {
    const float4* sp = (const float4*)((const float*)sstate + nd * 16);
    const float4* ap = (const float4*)((const float*)alog + (size_t)d * 16);
#pragma unroll
    for (int i = 0; i < 4; i++) {
      float4 sv = sp[i], av = ap[i];
      stf[i * 4 + 0] = sv.x; stf[i * 4 + 1] = sv.y; stf[i * 4 + 2] = sv.z; stf[i * 4 + 3] = sv.w;
      alf[i * 4 + 0] = av.x; alf[i * 4 + 1] = av.y; alf[i * 4 + 2] = av.z; alf[i * 4 + 3] = av.w;
    }
  }
  float y = 0.f;
#pragma unroll
  for (int s = 0; s < 16; s++) {
    float Aa = -__expf(alf[s]);
    float dA = __expf(dtv * Aa);
    float h = dA * stf[s] + dtv * Bsh[s] * uv;
    y += h * Csh[s];
  }
  y += ldsc(dparam, d, bf) * uv;
  z[nd] = y * rv;
}

__global__ __launch_bounds__(256) void cvt_k(const float* __restrict__ in,
                                             void* __restrict__ out, int n,
                                             const u32* __restrict__ probe) {
  const bool bf = (probe[0] != 0u);
  int i = blockIdx.x * 256 + threadIdx.x;
  if (i < n) {
    if (bf) ((u16*)out)[i] = f2bf(in[i]);
    else    ((float*)out)[i] = in[i];
  }
}

extern "C" void kernel_launch(void* const* d_in, const int* in_sizes, int n_in,
                              void* d_out, int out_size, void* d_ws, size_t ws_size,
                              hipStream_t stream) {
  const void* x         = d_in[0];
  // d_in[1] = conv_state0 (unused by reference)
  const void* cs1       = d_in[2];
  const void* cs2       = d_in[3];
  const void* cs3       = d_in[4];
  const void* ssm_state = d_in[5];
  const void* ssm_proj  = d_in[6];
  const void* mlp_proj  = d_in[7];
  const void* down_proj = d_in[8];
  const void* conv_w    = d_in[9];
  const void* conv_b    = d_in[10];
  const void* x_proj_w  = d_in[11];
  const void* dt_proj_w = d_in[12];
  const void* dt_proj_b = d_in[13];
  const void* A_log     = d_in[14];
  const void* D_param   = d_in[15];
  const u32*  probe     = (const u32*)A_log;  // A_log[0][0] = log(1) = 0; f32 word == 0, bf16 word != 0

  float* ws   = (float*)d_ws;
  float* u    = ws + U_OFF;
  float* res  = ws + RES_OFF;
  float* dt   = ws + DT_OFF;
  float* z    = ws + Z_OFF;
  float* proj = ws + PROJ_OFF;
  float* oacc = ws + OACC_OFF;

  // zero the atomic-accumulated buffers (ws is poisoned 0xAA each call)
  hipMemsetAsync(proj, 0, (size_t)TOKENS * NP * sizeof(float), stream);
  hipMemsetAsync(oacc, 0, (size_t)TOKENS * DM * sizeof(float), stream);

  // K1: x @ [ssm_proj | mlp_proj]; first half fuses conv+silu -> u, second -> res
  {
    GemmP p{};
    p.A = x; p.lda = DM; p.a_ws = 0;
    p.B = ssm_proj; p.B2 = mlp_proj;
    p.C = u; p.C2 = res;
    p.ldb = DI; p.ldc = DI;
    p.ksteps = DM / 32; p.nx_half = 80;
    p.epi1 = 1; p.epi2 = 0; p.atomic_ = 0;
    p.bias = conv_b; p.cs1 = cs1; p.cs2 = cs2; p.cs3 = cs3; p.cw = conv_w;
    p.probe = probe;
    gemm_k<<<dim3(160, 1), 256, 0, stream>>>(p);
  }
  // K3: proj = u @ x_proj_w  (split-K 40, atomic)
  {
    GemmP p{};
    p.A = u; p.lda = DI; p.a_ws = 1;
    p.B = x_proj_w; p.B2 = nullptr;
    p.C = proj; p.C2 = nullptr;
    p.ldb = NP; p.ldc = NP;
    p.ksteps = 4; p.nx_half = 1 << 30;
    p.epi1 = 0; p.epi2 = 0; p.atomic_ = 1;
    p.probe = probe;
    gemm_k<<<dim3(3, 40), 256, 0, stream>>>(p);
  }
  // K4: dt = softplus(proj[:, :160] @ dt_proj_w + b)
  {
    GemmP p{};
    p.A = proj; p.lda = NP; p.a_ws = 1;
    p.B = dt_proj_w; p.B2 = nullptr;
    p.C = dt; p.C2 = nullptr;
    p.ldb = DI; p.ldc = DI;
    p.ksteps = NR / 32; p.nx_half = 1 << 30;
    p.epi1 = 2; p.epi2 = 0; p.atomic_ = 0;
    p.bias = dt_proj_b;
    p.probe = probe;
    gemm_k<<<dim3(DI / 64, 1), 256, 0, stream>>>(p);
  }
  // K5: SSM scan -> z = y * res
  ssm_k<<<dim3(DI / 256, TOKENS), 256, 0, stream>>>(
      ssm_state, A_log, D_param, proj, dt, u, res, z, probe);
  // K6: oacc = z @ down_proj (split-K 4, atomic f32)
  {
    GemmP p{};
    p.A = z; p.lda = DI; p.a_ws = 1;
    p.B = down_proj; p.B2 = nullptr;
    p.C = oacc; p.C2 = nullptr;
    p.ldb = DM; p.ldc = DM;
    p.ksteps = 40; p.nx_half = 1 << 30;
    p.epi1 = 0; p.epi2 = 0; p.atomic_ = 1;
    p.probe = probe;
    gemm_k<<<dim3(DM / 64, 4), 256, 0, stream>>>(p);
  }
  // K7: output convert (bf16 or f32 passthrough per sniffed dtype)
  cvt_k<<<dim3((out_size + 255) / 256), 256, 0, stream>>>(oacc, d_out, out_size, probe);
}

// Round 4
// 321.716 us; speedup vs baseline: 1.4938x; 1.4938x over previous
//
#include <hip/hip_runtime.h>

using u16 = unsigned short;
using u32 = unsigned int;

typedef __attribute__((ext_vector_type(8))) short short8;
typedef __attribute__((ext_vector_type(4))) float floatx4;

constexpr int TOKENS = 128;   // N (M dim of GEMMs)
constexpr int DM = 2560;      // D
constexpr int DI = 5120;      // DIN
constexpr int NS = 16;        // S
constexpr int NR = 160;       // R
constexpr int NP = 192;       // R + 2S

// workspace layout (floats). z aliases xs_acc (xs dead after epi_u).
constexpr size_t XS_OFF   = 0;                                  // xs_acc, then z
constexpr size_t RES_OFF  = XS_OFF  + (size_t)TOKENS * DI;
constexpr size_t U_OFF    = RES_OFF + (size_t)TOKENS * DI;
constexpr size_t DT_OFF   = U_OFF   + (size_t)TOKENS * DI;      // dt_acc (raw, pre-softplus)
constexpr size_t PROJ_OFF = DT_OFF  + (size_t)TOKENS * DI;
constexpr size_t OACC_OFF = PROJ_OFF + (size_t)TOKENS * NP;

__device__ __forceinline__ float bf2f(u16 h) {
  u32 u = ((u32)h) << 16;
  return __builtin_bit_cast(float, u);
}
__device__ __forceinline__ u16 f2bf(float f) {
  u32 u = __builtin_bit_cast(u32, f);
  u += 0x7FFFu + ((u >> 16) & 1u);   // RNE
  return (u16)(u >> 16);
}
__device__ __forceinline__ u32 pk2(float a, float b) {
  return (u32)f2bf(a) | ((u32)f2bf(b) << 16);
}
__device__ __forceinline__ float ldsc(const void* p, size_t i, bool bf) {
  return bf ? bf2f(((const u16*)p)[i]) : ((const float*)p)[i];
}
// load 8 consecutive elements as packed bf16 (uint4); i must be multiple of 8
__device__ __forceinline__ uint4 ld8(const void* p, size_t i, bool bf) {
  if (bf) return *(const uint4*)((const u16*)p + i);
  const float4* f = (const float4*)((const float*)p + i);
  float4 a = f[0], b = f[1];
  return (uint4){pk2(a.x, a.y), pk2(a.z, a.w), pk2(b.x, b.y), pk2(b.z, b.w)};
}

struct GemmP {
  const void* A; int lda; int a_ws;   // a_ws: A is f32 workspace
  const void* B; const void* B2;     // raw inputs (bf16/f32 per probe)
  float* C; float* C2;
  int ldb; int ldc;
  int ksteps;          // BK=32 steps per split; kstart = blockIdx.y*ksteps*32
  int nx_half;         // blockIdx.x >= nx_half -> B2/C2
  const u32* probe;    // first word of A_log: 0 => inputs f32, else bf16
};

// BM=128 BN=64 BK=32, 256 threads = 4 waves (2x2), wave tile 64x32 (4x2 mfma 16x16x32).
// All GEMMs atomically accumulate raw f32 into C (split-K); epilogues live in consumers.
__global__ __launch_bounds__(256, 4) void gemm_k(GemmP p) {
  __shared__ u16 As[128 * 40];  // [m][k], row stride 40 elems (80B, 16B-aligned, padded)
  __shared__ u16 Bs[32 * 64];   // [k][n] with 32B rotation swizzle per (k>>3)

  const bool bf = (p.probe[0] != 0u);
  const int tid = threadIdx.x;
  const int bx = blockIdx.x;
  const void* B = p.B; float* C = p.C;
  int nblk = bx;
  if (bx >= p.nx_half) { B = p.B2; C = p.C2; nblk = bx - p.nx_half; }
  const int n0 = nblk * 64;
  const int kstart = blockIdx.y * p.ksteps * 32;

  const int wave = tid >> 6, lane = tid & 63;
  const int q = lane >> 4, l16 = lane & 15;
  const int wx = wave & 1, wy = wave >> 1;

  const bool a_f32 = p.a_ws || !bf;
  const int am = (tid + 0) >> 2, asg = tid & 3;          // A row/chunk for id=tid
  const int am2 = (tid + 256) >> 2;                       // id=tid+256
  const int bk = tid >> 3, bsg = tid & 7;

  floatx4 acc[4][2];
#pragma unroll
  for (int mi = 0; mi < 4; mi++)
#pragma unroll
    for (int ni = 0; ni < 2; ni++) acc[mi][ni] = (floatx4){0.f, 0.f, 0.f, 0.f};

  uint4 aW[2], bW;
  auto load_tiles = [&](int ks, uint4* aO, uint4& bO) {
    const int kbase = kstart + ks * 32;
    if (!a_f32) {
      aO[0] = *(const uint4*)((const u16*)p.A + (size_t)am * p.lda + kbase + asg * 8);
      aO[1] = *(const uint4*)((const u16*)p.A + (size_t)am2 * p.lda + kbase + asg * 8);
    } else {
      const float4* f0 = (const float4*)((const float*)p.A + (size_t)am * p.lda + kbase + asg * 8);
      const float4* f1 = (const float4*)((const float*)p.A + (size_t)am2 * p.lda + kbase + asg * 8);
      float4 a0 = f0[0], a1 = f0[1], b0 = f1[0], b1 = f1[1];
      aO[0] = (uint4){pk2(a0.x, a0.y), pk2(a0.z, a0.w), pk2(a1.x, a1.y), pk2(a1.z, a1.w)};
      aO[1] = (uint4){pk2(b0.x, b0.y), pk2(b0.z, b0.w), pk2(b1.x, b1.y), pk2(b1.z, b1.w)};
    }
    bO = ld8(B, (size_t)(kbase + bk) * p.ldb + n0 + bsg * 8, bf);
  };

  load_tiles(0, aW, bW);

  for (int ks = 0;;) {
    __syncthreads();  // prev compute done before overwriting LDS
    *(uint4*)&As[am * 40 + asg * 8] = aW[0];
    *(uint4*)&As[am2 * 40 + asg * 8] = aW[1];
    {
      int off = ((bsg << 4) + ((bk >> 3) << 5)) & 127;  // byte offset, 16B-aligned
      *(uint4*)&Bs[bk * 64 + (off >> 1)] = bW;
    }
    __syncthreads();

    // prefetch next tile's global data (overlaps with LDS reads + MFMA below)
    uint4 aN[2], bN;
    const bool more = (ks + 1 < p.ksteps);
    if (more) load_tiles(ks + 1, aN, bN);

    // ---- compute ----
    short8 afr[4];
#pragma unroll
    for (int mi = 0; mi < 4; mi++)
      afr[mi] = __builtin_bit_cast(short8,
          *(const uint4*)&As[(wy * 64 + mi * 16 + l16) * 40 + q * 8]);
    short8 bfr[2];
#pragma unroll
    for (int ni = 0; ni < 2; ni++) {
      int nl2 = (wx * 32 + ni * 16 + l16) * 2;
      int boff = (nl2 + (q << 5)) & 127;
      const u16* bp = &Bs[q * 512 + (boff >> 1)];
      short8 b;
#pragma unroll
      for (int j = 0; j < 8; j++) b[j] = (short)bp[j * 64];
      bfr[ni] = b;
    }
#pragma unroll
    for (int mi = 0; mi < 4; mi++)
#pragma unroll
      for (int ni = 0; ni < 2; ni++)
        acc[mi][ni] = __builtin_amdgcn_mfma_f32_16x16x32_bf16(
            afr[mi], bfr[ni], acc[mi][ni], 0, 0, 0);

    if (!more) break;
    aW[0] = aN[0]; aW[1] = aN[1]; bW = bN;
    ks++;
  }

  // ---- epilogue: atomic raw accumulate. row = wy*64+mi*16+q*4+r, col = n0+wx*32+ni*16+l16
#pragma unroll
  for (int ni = 0; ni < 2; ni++) {
    int col = n0 + wx * 32 + ni * 16 + l16;
#pragma unroll
    for (int mi = 0; mi < 4; mi++) {
      floatx4 v = acc[mi][ni];
#pragma unroll
      for (int r = 0; r < 4; r++) {
        int row = wy * 64 + mi * 16 + q * 4 + r;
        atomicAdd(&C[(size_t)row * p.ldc + col], v[r]);
      }
    }
  }
}

// u = silu(conv_bias + w0*cs1 + w1*cs2 + w2*cs3 + w3*xs). grid (DI/256, TOKENS)
__global__ __launch_bounds__(256) void epi_u_k(
    const float* __restrict__ xs_acc, const void* __restrict__ cs1,
    const void* __restrict__ cs2, const void* __restrict__ cs3,
    const void* __restrict__ cw, const void* __restrict__ cb,
    float* __restrict__ u, const u32* __restrict__ probe) {
  const bool bf = (probe[0] != 0u);
  const int n = blockIdx.y;
  const int d = blockIdx.x * 256 + threadIdx.x;
  const size_t nd = (size_t)n * DI + d;
  float cv = ldsc(cb, d, bf) + ldsc(cw, d, bf) * ldsc(cs1, nd, bf) +
             ldsc(cw, DI + d, bf) * ldsc(cs2, nd, bf) +
             ldsc(cw, 2 * DI + d, bf) * ldsc(cs3, nd, bf) +
             ldsc(cw, 3 * DI + d, bf) * xs_acc[nd];   // FIX: w3 factor was dropped in r3
  u[nd] = cv / (1.0f + __expf(-cv));
}

// SSM scan + dt softplus + fused * res. grid (DI/256, TOKENS)
__global__ __launch_bounds__(256) void ssm_k(
    const void* __restrict__ sstate, const void* __restrict__ alog,
    const void* __restrict__ dparam, const void* __restrict__ dtb,
    const float* __restrict__ proj, const float* __restrict__ dtacc,
    const float* __restrict__ u, const float* __restrict__ res,
    float* __restrict__ z, const u32* __restrict__ probe) {
  const bool bf = (probe[0] != 0u);
  const int n = blockIdx.y;
  const int d = blockIdx.x * 256 + threadIdx.x;
  __shared__ float Bsh[NS], Csh[NS];
  if (threadIdx.x < NS)
    Bsh[threadIdx.x] = proj[(size_t)n * NP + NR + threadIdx.x];
  else if (threadIdx.x < 2 * NS)
    Csh[threadIdx.x - NS] = proj[(size_t)n * NP + NR + threadIdx.x];
  __syncthreads();
  const size_t nd = (size_t)n * DI + d;
  const float uv = u[nd], rv = res[nd];
  float sv = dtacc[nd] + ldsc(dtb, d, bf);
  const float dtv = (sv > 20.0f) ? sv : log1pf(__expf(sv));  // softplus

  float stf[16], alf[16];
  if (bf) {
    u16 st[16], al[16];
    const uint4* sp = (const uint4*)((const u16*)sstate + nd * 16);
    *(uint4*)&st[0] = sp[0]; *(uint4*)&st[8] = sp[1];
    const uint4* ap = (const uint4*)((const u16*)alog + (size_t)d * 16);
    *(uint4*)&al[0] = ap[0]; *(uint4*)&al[8] = ap[1];
#pragma unroll
    for (int s = 0; s < 16; s++) { stf[s] = bf2f(st[s]); alf[s] = bf2f(al[s]); }
  } else {
    const float4* sp = (const float4*)((const float*)sstate + nd * 16);
    const float4* ap = (const float4*)((const float*)alog + (size_t)d * 16);
#pragma unroll
    for (int i = 0; i < 4; i++) {
      float4 s4 = sp[i], a4 = ap[i];
      stf[i * 4 + 0] = s4.x; stf[i * 4 + 1] = s4.y; stf[i * 4 + 2] = s4.z; stf[i * 4 + 3] = s4.w;
      alf[i * 4 + 0] = a4.x; alf[i * 4 + 1] = a4.y; alf[i * 4 + 2] = a4.z; alf[i * 4 + 3] = a4.w;
    }
  }
  float y = 0.f;
#pragma unroll
  for (int s = 0; s < 16; s++) {
    float Aa = -__expf(alf[s]);
    float dA = __expf(dtv * Aa);
    float h = dA * stf[s] + dtv * Bsh[s] * uv;
    y += h * Csh[s];
  }
  y += ldsc(dparam, d, bf) * uv;
  z[nd] = y * rv;
}

__global__ __launch_bounds__(256) void cvt_k(const float* __restrict__ in,
                                             void* __restrict__ out, int n,
                                             const u32* __restrict__ probe) {
  const bool bf = (probe[0] != 0u);
  int i = blockIdx.x * 256 + threadIdx.x;
  if (i < n) {
    if (bf) ((u16*)out)[i] = f2bf(in[i]);
    else    ((float*)out)[i] = in[i];
  }
}

extern "C" void kernel_launch(void* const* d_in, const int* in_sizes, int n_in,
                              void* d_out, int out_size, void* d_ws, size_t ws_size,
                              hipStream_t stream) {
  const void* x         = d_in[0];
  // d_in[1] = conv_state0 (unused by reference)
  const void* cs1       = d_in[2];
  const void* cs2       = d_in[3];
  const void* cs3       = d_in[4];
  const void* ssm_state = d_in[5];
  const void* ssm_proj  = d_in[6];
  const void* mlp_proj  = d_in[7];
  const void* down_proj = d_in[8];
  const void* conv_w    = d_in[9];
  const void* conv_b    = d_in[10];
  const void* x_proj_w  = d_in[11];
  const void* dt_proj_w = d_in[12];
  const void* dt_proj_b = d_in[13];
  const void* A_log     = d_in[14];
  const void* D_param   = d_in[15];
  const u32*  probe     = (const u32*)A_log;  // A_log[0][0]=log(1)=0: f32 word==0, bf16 word!=0

  float* ws     = (float*)d_ws;
  float* xs_acc = ws + XS_OFF;
  float* z      = ws + XS_OFF;   // alias: xs dead after epi_u
  float* res    = ws + RES_OFF;
  float* u      = ws + U_OFF;
  float* dtacc  = ws + DT_OFF;
  float* proj   = ws + PROJ_OFF;
  float* oacc   = ws + OACC_OFF;

  // zero all atomic-accumulated buffers (ws is poisoned 0xAA each call)
  hipMemsetAsync(xs_acc, 0, (size_t)TOKENS * DI * sizeof(float), stream);
  hipMemsetAsync(res,    0, (size_t)TOKENS * DI * sizeof(float), stream);
  hipMemsetAsync(dtacc,  0, (size_t)TOKENS * DI * sizeof(float), stream);
  hipMemsetAsync(proj,   0, (size_t)TOKENS * NP * sizeof(float), stream);
  hipMemsetAsync(oacc,   0, (size_t)TOKENS * DM * sizeof(float), stream);

  // K1: xs_acc = x @ ssm_proj ; res = x @ mlp_proj   (split-K 8)
  {
    GemmP p{};
    p.A = x; p.lda = DM; p.a_ws = 0;
    p.B = ssm_proj; p.B2 = mlp_proj;
    p.C = xs_acc; p.C2 = res;
    p.ldb = DI; p.ldc = DI;
    p.ksteps = DM / 32 / 8; p.nx_half = 80;
    p.probe = probe;
    gemm_k<<<dim3(160, 8), 256, 0, stream>>>(p);
  }
  // E1: u = silu(conv(xs_acc, states))
  epi_u_k<<<dim3(DI / 256, TOKENS), 256, 0, stream>>>(
      xs_acc, cs1, cs2, cs3, conv_w, conv_b, u, probe);
  // K3: proj = u @ x_proj_w  (split-K 40)
  {
    GemmP p{};
    p.A = u; p.lda = DI; p.a_ws = 1;
    p.B = x_proj_w; p.B2 = nullptr;
    p.C = proj; p.C2 = nullptr;
    p.ldb = NP; p.ldc = NP;
    p.ksteps = 4; p.nx_half = 1 << 30;
    p.probe = probe;
    gemm_k<<<dim3(3, 40), 256, 0, stream>>>(p);
  }
  // K4: dtacc = proj[:, :160] @ dt_proj_w  (split-K 5; softplus+bias in ssm_k)
  {
    GemmP p{};
    p.A = proj; p.lda = NP; p.a_ws = 1;
    p.B = dt_proj_w; p.B2 = nullptr;
    p.C = dtacc; p.C2 = nullptr;
    p.ldb = DI; p.ldc = DI;
    p.ksteps = 1; p.nx_half = 1 << 30;
    p.probe = probe;
    gemm_k<<<dim3(DI / 64, 5), 256, 0, stream>>>(p);
  }
  // K5: SSM scan -> z = y * res   (z aliases xs_acc)
  ssm_k<<<dim3(DI / 256, TOKENS), 256, 0, stream>>>(
      ssm_state, A_log, D_param, dt_proj_b, proj, dtacc, u, res, z, probe);
  // K6: oacc = z @ down_proj (split-K 16)
  {
    GemmP p{};
    p.A = z; p.lda = DI; p.a_ws = 1;
    p.B = down_proj; p.B2 = nullptr;
    p.C = oacc; p.C2 = nullptr;
    p.ldb = DM; p.ldc = DM;
    p.ksteps = DI / 32 / 16; p.nx_half = 1 << 30;
    p.probe = probe;
    gemm_k<<<dim3(DM / 64, 16), 256, 0, stream>>>(p);
  }
  // K7: output convert (bf16 or f32 passthrough per sniffed dtype)
  cvt_k<<<dim3((out_size + 255) / 256), 256, 0, stream>>>(oacc, d_out, out_size, probe);
}